// Round 1
// baseline (574.052 us; speedup 1.0000x reference)
//
#include <hip/hip_runtime.h>

#define BB 64
#define SS 512
#define DD 768
#define TT 64

// ---------------------------------------------------------------------------
// Kernel 1: emissions GEMM  em[b*512+s][t] = sum_d x[b,s,d]*W[t,d] + bias[t]
// fp32 vector FMA, sequential-k accumulation (deterministic).
// Tile: 128 rows x 64 cols per block, 256 threads, thread tile 8x4.
// ---------------------------------------------------------------------------
__global__ __launch_bounds__(256) void emis_gemm(
    const float* __restrict__ X, const float* __restrict__ W,
    const float* __restrict__ bias, float* __restrict__ em)
{
    __shared__ __align__(16) float Xs[16][132];  // [k][m], padded
    __shared__ __align__(16) float Ws[16][68];   // [k][t], padded

    const int tid = threadIdx.x;
    const int m0  = blockIdx.x * 128;
    const int tm  = tid >> 4;    // 0..15 -> 8 rows each
    const int tn  = tid & 15;    // 0..15 -> 4 cols each

    const int lm  = tid >> 2;    // X load: row (and +64)
    const int lkq = tid & 3;     // X load: k-quad
    const int wt  = tid & 63;    // W load: row t
    const int wkq = tid >> 6;    // W load: k-quad

    float acc[8][4];
#pragma unroll
    for (int i = 0; i < 8; i++)
#pragma unroll
        for (int j = 0; j < 4; j++) acc[i][j] = 0.f;

    float4 xr0, xr1, wr;
    // prologue: stage tile 0 into regs
    xr0 = *(const float4*)&X[(size_t)(m0 + lm) * DD + lkq * 4];
    xr1 = *(const float4*)&X[(size_t)(m0 + lm + 64) * DD + lkq * 4];
    wr  = *(const float4*)&W[(size_t)wt * DD + wkq * 4];

    for (int t = 0; t < 48; t++) {
        // regs -> LDS (transposed)
        Xs[lkq * 4 + 0][lm] = xr0.x;  Xs[lkq * 4 + 1][lm] = xr0.y;
        Xs[lkq * 4 + 2][lm] = xr0.z;  Xs[lkq * 4 + 3][lm] = xr0.w;
        Xs[lkq * 4 + 0][lm + 64] = xr1.x;  Xs[lkq * 4 + 1][lm + 64] = xr1.y;
        Xs[lkq * 4 + 2][lm + 64] = xr1.z;  Xs[lkq * 4 + 3][lm + 64] = xr1.w;
        Ws[wkq * 4 + 0][wt] = wr.x;  Ws[wkq * 4 + 1][wt] = wr.y;
        Ws[wkq * 4 + 2][wt] = wr.z;  Ws[wkq * 4 + 3][wt] = wr.w;
        __syncthreads();

        if (t < 47) {  // prefetch next tile (latency hidden under compute)
            const int k0 = (t + 1) * 16;
            xr0 = *(const float4*)&X[(size_t)(m0 + lm) * DD + k0 + lkq * 4];
            xr1 = *(const float4*)&X[(size_t)(m0 + lm + 64) * DD + k0 + lkq * 4];
            wr  = *(const float4*)&W[(size_t)wt * DD + k0 + wkq * 4];
        }

#pragma unroll
        for (int k = 0; k < 16; k++) {
            float a[8], bv[4];
            *(float4*)&a[0] = *(const float4*)&Xs[k][tm * 8];
            *(float4*)&a[4] = *(const float4*)&Xs[k][tm * 8 + 4];
            *(float4*)&bv[0] = *(const float4*)&Ws[k][tn * 4];
#pragma unroll
            for (int i = 0; i < 8; i++)
#pragma unroll
                for (int j = 0; j < 4; j++)
                    acc[i][j] = fmaf(a[i], bv[j], acc[i][j]);
        }
        __syncthreads();
    }

    const float4 bv4 = *(const float4*)&bias[tn * 4];
#pragma unroll
    for (int i = 0; i < 8; i++) {
        const size_t row = (size_t)(m0 + tm * 8 + i);
        float4 o;
        o.x = acc[i][0] + bv4.x;  o.y = acc[i][1] + bv4.y;
        o.z = acc[i][2] + bv4.z;  o.w = acc[i][3] + bv4.w;
        *(float4*)&em[row * TT + tn * 4] = o;
    }
}

// ---------------------------------------------------------------------------
// Kernel 2: Viterbi scan + path-doubling backtrack. One block per batch.
// 256 threads: cur = wave*16 + (lane>>2); pg = lane&3 covers 16 prevs.
// Replicates reference rounding: v = (score[prev] + trans[prev][cur]) + em[cur]
// and first-index argmax tie-breaking exactly.
// ---------------------------------------------------------------------------
__global__ __launch_bounds__(256) void viterbi(
    const float* __restrict__ em, const float* __restrict__ trans,
    unsigned char* __restrict__ histG, unsigned char* __restrict__ tabA,
    unsigned char* __restrict__ tabB, int* __restrict__ out)
{
    __shared__ __align__(16) float em_lds[2][64][TT];   // 32 KB, 64-step chunks
    __shared__ __align__(16) float score_lds[2][TT];

    const int b   = blockIdx.x;
    const int tid = threadIdx.x;
    const int lane = tid & 63;
    const int cur_local = lane >> 2;
    const int pg  = lane & 3;
    const int wv  = tid >> 6;
    const int cur = wv * 16 + cur_local;
    const int prev0 = pg * 16;

    const float* emb = em + (size_t)b * SS * TT;
    unsigned char* hG = histG + (size_t)b * SS * TT;

    // transition column for this (pg, cur): 16 registers
    float treg[16];
#pragma unroll
    for (int i = 0; i < 16; i++) treg[i] = trans[(prev0 + i) * TT + cur];

    float4 ereg[4];
    // stage chunk 0
    {
        const float4* src = (const float4*)emb;
#pragma unroll
        for (int i = 0; i < 4; i++) ereg[i] = src[tid + i * 256];
        float4* dst = (float4*)&em_lds[0][0][0];
#pragma unroll
        for (int i = 0; i < 4; i++) dst[tid + i * 256] = ereg[i];
    }
    __syncthreads();
    if (tid < 64) score_lds[0][tid] = em_lds[0][0][tid];  // init = em[s=0]
    // issue chunk 1 loads (land in regs; consumed at chunk boundary)
    {
        const float4* src = (const float4*)(emb + 4096);
#pragma unroll
        for (int i = 0; i < 4; i++) ereg[i] = src[tid + i * 256];
    }
    __syncthreads();

    int p = 0;
    for (int c = 0; c < 8; c++) {
        const int buf = c & 1;
        const int s_begin = (c == 0) ? 1 : c * 64;
        const int s_end = c * 64 + 64;
        for (int s = s_begin; s < s_end; s++) {
            const int sl = s - c * 64;
            const float em_v = em_lds[buf][sl][cur];
            const float* sc = score_lds[p];

            // 4 sub-chains of 4 (ascending prev; strict > keeps first max)
            float bv[4]; int ba[4];
#pragma unroll
            for (int ch = 0; ch < 4; ch++) {
                const int base = prev0 + ch * 4;
                float v = (sc[base] + treg[ch * 4]) + em_v;
                bv[ch] = v; ba[ch] = base;
#pragma unroll
                for (int i = 1; i < 4; i++) {
                    float v2 = (sc[base + i] + treg[ch * 4 + i]) + em_v;
                    if (v2 > bv[ch]) { bv[ch] = v2; ba[ch] = base + i; }
                }
            }
            // ordered merges: higher chain wins only on strict >
            if (bv[1] > bv[0]) { bv[0] = bv[1]; ba[0] = ba[1]; }
            if (bv[3] > bv[2]) { bv[2] = bv[3]; ba[2] = ba[3]; }
            if (bv[2] > bv[0]) { bv[0] = bv[2]; ba[0] = ba[2]; }
            float best = bv[0]; int barg = ba[0];

            // cross-pg reduce (arg-aware tie-break: lower prev wins)
#pragma unroll
            for (int m = 1; m <= 2; m <<= 1) {
                float vo = __shfl_xor(best, m, 64);
                int   ao = __shfl_xor(barg, m, 64);
                if (vo > best || (vo == best && ao < barg)) { best = vo; barg = ao; }
            }

            if (pg == 0) {
                score_lds[p ^ 1][cur] = best;
                hG[s * TT + cur] = (unsigned char)barg;
            }
            __syncthreads();
            p ^= 1;
        }
        if (c < 7) {
            // write prefetched chunk c+1 into the other buffer
            float4* dst = (float4*)&em_lds[buf ^ 1][0][0];
#pragma unroll
            for (int i = 0; i < 4; i++) dst[tid + i * 256] = ereg[i];
            if (c < 6) {  // issue chunk c+2
                const float4* src = (const float4*)(emb + (size_t)(c + 2) * 4096);
#pragma unroll
                for (int i = 0; i < 4; i++) ereg[i] = src[tid + i * 256];
            }
            __syncthreads();
        }
    }

    // final argmax over score_lds[p] (first-max), redundantly per wave
    float fv = score_lds[p][lane];
    int   fa = lane;
#pragma unroll
    for (int m = 1; m <= 32; m <<= 1) {
        float vo = __shfl_xor(fv, m, 64);
        int   ao = __shfl_xor(fa, m, 64);
        if (vo > fv || (vo == fv && ao < fa)) { fv = vo; fa = ao; }
    }
    const int best_tag = fa;

    // ---- backtrack via path doubling on the backpointer table ----
    // G[s][t] = tag at s given tag at min(s+d,511)=t ; init d=1: G[s]=hist[s+1]
    unsigned char* A  = tabA + (size_t)b * SS * TT;
    unsigned char* Bt = tabB + (size_t)b * SS * TT;
    for (int idx = tid; idx < 511 * 64; idx += 256) A[idx] = hG[idx + 64];
    __syncthreads();

    unsigned char* curT = A;
    unsigned char* nxtT = Bt;
    for (int d = 1; d < 511; d <<= 1) {
        for (int idx = tid; idx < 511 * 64; idx += 256) {
            const int s = idx >> 6;
            const int t = idx & 63;
            unsigned char r;
            if (s + d >= 511) {
                r = curT[idx];
            } else {
                unsigned char mid = curT[(s + d) * 64 + t];
                r = curT[s * 64 + mid];
            }
            nxtT[idx] = r;
        }
        __syncthreads();
        unsigned char* tmp = curT; curT = nxtT; nxtT = tmp;
    }

    // write tags
    for (int s = tid; s < SS; s += 256) {
        const int tag = (s == 511) ? best_tag : (int)curT[(size_t)s * 64 + best_tag];
        out[(size_t)b * SS + s] = tag;
    }
}

// ---------------------------------------------------------------------------
extern "C" void kernel_launch(void* const* d_in, const int* in_sizes, int n_in,
                              void* d_out, int out_size, void* d_ws, size_t ws_size,
                              hipStream_t stream)
{
    const float* X     = (const float*)d_in[0];  // [64,512,768]
    const float* W     = (const float*)d_in[1];  // [64,768]
    const float* bias  = (const float*)d_in[2];  // [64]
    const float* trans = (const float*)d_in[3];  // [64,64]
    int* out = (int*)d_out;                      // [64,512] int32

    char* ws = (char*)d_ws;
    float*         em    = (float*)ws;                         // 8,388,608 B
    unsigned char* histG = (unsigned char*)(ws + 8388608);     // 2,097,152 B
    unsigned char* tabA  = (unsigned char*)(ws + 10485760);    // 2,097,152 B
    unsigned char* tabB  = (unsigned char*)(ws + 12582912);    // 2,097,152 B

    emis_gemm<<<dim3(256), dim3(256), 0, stream>>>(X, W, bias, em);
    viterbi<<<dim3(64), dim3(256), 0, stream>>>(em, trans, histG, tabA, tabB, out);
}